// Round 14
// baseline (489.612 us; speedup 1.0000x reference)
//
#include <hip/hip_runtime.h>
#include <stdint.h>
#include <stddef.h>

typedef float f32x4 __attribute__((ext_vector_type(4)));
typedef int   i32x4 __attribute__((ext_vector_type(4)));
typedef _Float16 f16;
typedef _Float16 f16x8 __attribute__((ext_vector_type(8)));
typedef _Float16 f16x4 __attribute__((ext_vector_type(4)));

#define NB 4096  // batch

// Tiled operand layout (= LDS tile order): 128-row M-tiles, BK=32 K-blocks,
// within block: [kq(4)][row(128)][8 f16]. One wave stages 1KB contiguous;
// a 128x128 tile (4 K-blocks) is one contiguous 32KB region.
__device__ __forceinline__ size_t tiled_off(int m, int k, int K) {
  return (size_t)(m >> 7) * ((size_t)128 * K) + (size_t)(k >> 5) * 4096 +
         (size_t)(((k >> 3) & 3) * 1024 + (m & 127) * 8 + (k & 7));
}

// async global->LDS, 16B per lane, wave-uniform LDS base + lane*16
__device__ __forceinline__ void gload_lds16(const f16* g, f16* l) {
  __builtin_amdgcn_global_load_lds(
      (const __attribute__((address_space(1))) void*)g,
      (__attribute__((address_space(3))) void*)l, 16, 0, 0);
}

struct GemmArgs {
  const f16* A[16];
  const f16* W[16];
  const float* bias[16];
  void* C[16];
  int N, K;
};

// ---------------------------------------------------------------------------
// 128x128 2-phase kernel, BK=32 (r10-proven: 45.7us/dispatch, ~755 TF).
// 256 thr (4 waves 2x2), 32KB LDS (As 2-buf | Bs 2-buf, aliased with C
// bounce), global_load_lds staging, __syncthreads double-buffer. Bounce-store
// per-lane-constant XOR swizzle -> conflict-free (r10: SQ_LDS_BANK_CONFLICT=0).
// OMODE: 0 = f32 row-major (guarded), 2 = f16 tiled.
// ---------------------------------------------------------------------------
template<bool RELU, int OMODE>
__global__ __launch_bounds__(256, 4)
void gemm_kernel(GemmArgs args) {
  // XCD-aware bijective block swizzle (all grids here have nwg % 8 == 0)
  const int nwg = gridDim.x * gridDim.y * gridDim.z;
  int bid = blockIdx.x + gridDim.x * (blockIdx.y + gridDim.y * blockIdx.z);
  if ((nwg & 7) == 0) {
    const int cpx = nwg >> 3;
    bid = (bid & 7) * cpx + (bid >> 3);
  }
  const int gx  = bid % gridDim.x;
  const int rem = bid / gridDim.x;
  const int gy  = rem % gridDim.y;
  const int g   = rem / gridDim.y;
  const int n0 = gx * 128, m0 = gy * 128;

  const int tid = threadIdx.x;
  const int lane = tid & 63;
  const int wid = tid >> 6;
  const int wr = wid >> 1, wc = wid & 1;
  const int N = args.N, K = args.K;

  // SH[0..8191] = As (2 bufs x 4096), SH[8192..16383] = Bs; reused as C bounce
  __shared__ __align__(16) f16 SH[16384];

  const f16* __restrict__ At = args.A[g] + (size_t)gy * 128 * K;
  const f16* __restrict__ Wt = args.W[g] + (size_t)gx * 128 * K;

  const int e0 = tid * 8, e1 = e0 + 2048;
  const int wb0 = (tid & ~63) * 8;
  const int wb1 = wb0 + 2048;

  f32x4 acc[4][4];
#pragma unroll
  for (int i = 0; i < 4; i++)
#pragma unroll
    for (int j = 0; j < 4; j++) { f32x4 z = {0.f, 0.f, 0.f, 0.f}; acc[i][j] = z; }

  const int nsteps = K >> 5;

  {
    f16* ab = SH;          // As buf 0
    f16* bb = SH + 8192;   // Bs buf 0
    gload_lds16(At + e0, ab + wb0);
    gload_lds16(At + e1, ab + wb1);
    gload_lds16(Wt + e0, bb + wb0);
    gload_lds16(Wt + e1, bb + wb1);
  }
  __syncthreads();

  for (int s = 0; s < nsteps; ++s) {
    const int cur = s & 1;
    if (s + 1 < nsteps) {
      const int nxt = cur ^ 1;
      const int off = (s + 1) << 12;
      f16* ab = SH + nxt * 4096;
      f16* bb = SH + 8192 + nxt * 4096;
      gload_lds16(At + off + e0, ab + wb0);
      gload_lds16(At + off + e1, ab + wb1);
      gload_lds16(Wt + off + e0, bb + wb0);
      gload_lds16(Wt + off + e1, bb + wb1);
    }
    const f16* ab = SH + cur * 4096;
    const f16* bb = SH + 8192 + cur * 4096;
    f16x8 af[4], bfv[4];
#pragma unroll
    for (int i = 0; i < 4; i++)
      af[i] = *(const f16x8*)(ab + (lane >> 4) * 1024 + (wr * 64 + i * 16 + (lane & 15)) * 8);
#pragma unroll
    for (int j = 0; j < 4; j++)
      bfv[j] = *(const f16x8*)(bb + (lane >> 4) * 1024 + (wc * 64 + j * 16 + (lane & 15)) * 8);
#pragma unroll
    for (int i = 0; i < 4; i++)
#pragma unroll
      for (int j = 0; j < 4; j++)
        acc[i][j] = __builtin_amdgcn_mfma_f32_16x16x32_f16(af[i], bfv[j], acc[i][j], 0, 0, 0);
    if (s + 1 < nsteps) __syncthreads();  // next buffer staged; cur reads done
  }

  const float* __restrict__ bias = args.bias[g];

  if constexpr (OMODE == 2) {
    // coalesced epilogue: bounce C-tile through LDS (tile is contiguous 32KB)
    // store-side swizzle: per-lane constant (bits 3,4) -> conflict-free
    __syncthreads();  // all LDS reads of the main loop complete
    const int swz = (((lane >> 3) & 1) << 3) | (((lane >> 5) & 1) << 4);
#pragma unroll
    for (int j = 0; j < 4; j++) {
      const int col = wc * 64 + j * 16 + (lane & 15);
      const float bv = bias[n0 + col];
#pragma unroll
      for (int i = 0; i < 4; i++) {
        const int rowb = wr * 64 + i * 16 + ((lane >> 4) << 2);
#pragma unroll
        for (int q = 0; q < 4; q++) {
          float v = acc[i][j][q] + bv;
          if (RELU) v = fmaxf(v, 0.0f);
          SH[tiled_off(rowb + q, col, 128) ^ swz] = (f16)v;
        }
      }
    }
    __syncthreads();
    f16* __restrict__ Cg = (f16*)args.C[g] + ((size_t)gy * N + n0) * 128;
#pragma unroll
    for (int r = 0; r < 8; r++) {
      const int c = r * 256 + tid;
      const int te = (c * 8) ^ (((c >> 7) & 1) << 3) ^ (((c >> 3) & 1) << 4);
      i32x4 v = *(const i32x4*)(SH + te);
      *(i32x4*)(Cg + (size_t)c * 8) = v;
    }
  } else {
    // f32 row-major, N-guarded scalar epilogue (heads only)
#pragma unroll
    for (int j = 0; j < 4; j++) {
      const int n = n0 + wc * 64 + j * 16 + (lane & 15);
      if (n < N) {
        const float bv = bias[n];
#pragma unroll
        for (int i = 0; i < 4; i++) {
          const int mrow = m0 + wr * 64 + i * 16 + ((lane >> 4) << 2);
#pragma unroll
          for (int q = 0; q < 4; q++) {
            float v = acc[i][j][q] + bv;
            if (RELU) v = fmaxf(v, 0.0f);
            ((float*)args.C[g])[(size_t)(mrow + q) * N + n] = v;
          }
        }
      }
    }
  }
}

// ---------------------------------------------------------------------------
// ALL weight transposes in ONE grid-stride dispatch, NO LDS, x4-vectorized:
// wave-job = (256 cols x 8 k-rows). Lane handles 4 consecutive cols:
// 8 x f32x4 row-loads (1KB coalesced wave-segments) + 4 x f16x8 tiled stores
// (4KB contiguous wave footprint). Descriptor table, explicit dstStride.
// ---------------------------------------------------------------------------
struct TSet {
  const float* srcA;
  const float* srcB;
  f16* dst;
  int nA, K, N, wx, dstStride, wvEnd;  // wx = ceil(N/256); wvEnd cumulative
};
struct TAll { TSet s[7]; };

__global__ __launch_bounds__(256)
void transpose_all_kernel(TAll args, int totalWv) {
  const int lane = threadIdx.x & 63;
  for (int wv = blockIdx.x * 4 + (threadIdx.x >> 6); wv < totalWv;
       wv += gridDim.x * 4) {
    int si = 0;
#pragma unroll
    for (int i = 0; i < 7; i++) si += (wv >= args.s[i].wvEnd) ? 1 : 0;
    if (si >= 7) continue;
    const TSet S = args.s[si];
    const int local = wv - (si ? args.s[si - 1].wvEnd : 0);
    const int perz = S.wx * (S.K >> 3);
    const int z = local / perz;
    const int r = local - z * perz;
    const int ko = r / S.wx;
    const int nb = (r - ko * S.wx) * 256 + lane * 4;
    const int K = S.K, N = S.N;
    const float* __restrict__ src =
        (z < S.nA) ? S.srcA + (size_t)z * K * N
                   : S.srcB + (size_t)(z - S.nA) * K * N;
    const int kbase = ko * 8;
    f16* __restrict__ dz = S.dst + (size_t)z * S.dstStride;
    if (nb + 3 < N) {
      f32x4 v[8];
#pragma unroll
      for (int e = 0; e < 8; e++)
        v[e] = *(const f32x4*)(src + (size_t)(kbase + e) * N + nb);
#pragma unroll
      for (int c = 0; c < 4; c++) {
        f16x8 o;
#pragma unroll
        for (int e = 0; e < 8; e++) o[e] = (f16)v[e][c];
        *(f16x8*)(dz + tiled_off(nb + c, kbase, K)) = o;
      }
    } else if (nb < N) {
#pragma unroll
      for (int c = 0; c < 4; c++) {
        if (nb + c < N) {
          f16x8 o;
#pragma unroll
          for (int e = 0; e < 8; e++)
            o[e] = (f16)src[(size_t)(kbase + e) * N + nb + c];
          *(f16x8*)(dz + tiled_off(nb + c, kbase, K)) = o;
        }
      }
    }
  }
}

// user_emb f32 row-major -> Uemb f16 tiled (K=512)
__global__ __launch_bounds__(256)
void cvt_kernel(const float* __restrict__ src, f16* __restrict__ dst, int n4) {
  int i = blockIdx.x * 256 + threadIdx.x;
  if (i < n4) {
    f32x4 v = *(const f32x4*)(src + (size_t)i * 4);
    f16x4 o = {(f16)v.x, (f16)v.y, (f16)v.z, (f16)v.w};
    const int e = i * 4;
    *(f16x4*)(dst + tiled_off(e >> 9, e & 511, 512)) = o;
  }
}

// ---------------------------------------------------------------------------
// bias packing + WT7 zeroing, one kernel
// ---------------------------------------------------------------------------
__global__ __launch_bounds__(256)
void pack_kernel(float* B1, const float* s1b1, const float* t1b1,
                 float* B2, const float* s1b2, const float* t1b2,
                 float* B3, const float* s2b1, const float* t2b1,
                 float* B4, const float* s2b2, const float* t2b2,
                 float* BT1, const float* chb1, const float* btb1,
                 float* BT2, const float* chb2, const float* btb2,
                 uint32_t* wt7z) {
  int i = blockIdx.x * 256 + threadIdx.x;
  if (i < 16384) { B1[i] = (i < 4096) ? s1b1[i] : t1b1[i - 4096]; return; }
  i -= 16384;
  if (i < 8192)  { B2[i] = (i < 2048) ? s1b2[i] : t1b2[i - 2048]; return; }
  i -= 8192;
  if (i < 16384) { B3[i] = (i < 4096) ? s2b1[i] : t2b1[i - 4096]; return; }
  i -= 16384;
  if (i < 8192)  { B4[i] = (i < 2048) ? s2b2[i] : t2b2[i - 2048]; return; }
  i -= 8192;
  if (i < 1536)  { BT1[i] = (i < 512) ? chb1[i] : btb1[i - 512]; return; }
  i -= 1536;
  if (i < 768)   { BT2[i] = (i < 256) ? chb2[i] : btb2[i - 256]; return; }
  i -= 768;
  if (i < 32768) wt7z[i] = 0u;
}

// ---------------------------------------------------------------------------
// Gates level 1 (full batch)
// ---------------------------------------------------------------------------
__global__ __launch_bounds__(256)
void gates1_kernel(const float* __restrict__ x, const float* __restrict__ g1W,
                   const float* __restrict__ g1b, const float* __restrict__ g1lW,
                   const float* __restrict__ g1lb, float* __restrict__ g1,
                   float* __restrict__ g1l) {
  const int lane = threadIdx.x & 63;
  const int b = blockIdx.x * 4 + (threadIdx.x >> 6);
  float xv[8];
#pragma unroll
  for (int i = 0; i < 8; i++) xv[i] = x[(size_t)b * 512 + lane + 64 * i];

#pragma unroll
  for (int t = 0; t < 3; t++) {
    float acc[8] = {0, 0, 0, 0, 0, 0, 0, 0};
#pragma unroll
    for (int i = 0; i < 8; i++) {
      const int d = lane + 64 * i;
      const float* wp = g1W + ((size_t)t * 512 + d) * 8;
      f32x4 w0 = *(const f32x4*)wp;
      f32x4 w1 = *(const f32x4*)(wp + 4);
      acc[0] += xv[i] * w0.x; acc[1] += xv[i] * w0.y;
      acc[2] += xv[i] * w0.z; acc[3] += xv[i] * w0.w;
      acc[4] += xv[i] * w1.x; acc[5] += xv[i] * w1.y;
      acc[6] += xv[i] * w1.z; acc[7] += xv[i] * w1.w;
    }
#pragma unroll
    for (int e = 0; e < 8; e++) {
#pragma unroll
      for (int off = 32; off >= 1; off >>= 1) acc[e] += __shfl_xor(acc[e], off);
      acc[e] += g1b[t * 8 + e];
    }
    float m = acc[0];
#pragma unroll
    for (int e = 1; e < 8; e++) m = fmaxf(m, acc[e]);
    float s = 0.f, p[8];
#pragma unroll
    for (int e = 0; e < 8; e++) { p[e] = expf(acc[e] - m); s += p[e]; }
    float inv = 1.0f / s;
    float mine = 0.f;
#pragma unroll
    for (int e = 0; e < 8; e++) if (lane == e) mine = p[e] * inv;
    if (lane < 8) g1[((size_t)t * NB + b) * 8 + lane] = mine;
  }

  float acc[16] = {};
#pragma unroll
  for (int i = 0; i < 8; i++) {
    const int d = lane + 64 * i;
    const float* wp = g1lW + (size_t)d * 16;
#pragma unroll
    for (int e4 = 0; e4 < 4; e4++) {
      f32x4 wv = *(const f32x4*)(wp + e4 * 4);
      acc[e4 * 4 + 0] += xv[i] * wv.x; acc[e4 * 4 + 1] += xv[i] * wv.y;
      acc[e4 * 4 + 2] += xv[i] * wv.z; acc[e4 * 4 + 3] += xv[i] * wv.w;
    }
  }
#pragma unroll
  for (int e = 0; e < 16; e++) {
#pragma unroll
    for (int off = 32; off >= 1; off >>= 1) acc[e] += __shfl_xor(acc[e], off);
    acc[e] += g1lb[e];
  }
  float m = acc[0];
#pragma unroll
  for (int e = 1; e < 16; e++) m = fmaxf(m, acc[e]);
  float s = 0.f, p[16];
#pragma unroll
  for (int e = 0; e < 16; e++) { p[e] = expf(acc[e] - m); s += p[e]; }
  float inv = 1.0f / s;
  float mine = 0.f;
#pragma unroll
  for (int e = 0; e < 16; e++) if (lane == e) mine = p[e] * inv;
  if (lane < 16) g1l[(size_t)b * 16 + lane] = mine;
}

// ---------------------------------------------------------------------------
// Gates level 2 (chunked): grid (Bc/4, 3). tf (3,Bc-tiled,512) f16.
// ---------------------------------------------------------------------------
__global__ __launch_bounds__(256)
void gates2_kernel(const f16* __restrict__ tf, const float* __restrict__ g2W,
                   const float* __restrict__ g2b, float* __restrict__ g2, int Bc) {
  const int lane = threadIdx.x & 63;
  const int b = blockIdx.x * 4 + (threadIdx.x >> 6);
  const int t = blockIdx.y;
  const f16* tb = tf + (size_t)t * Bc * 512;
  float xv[8];
#pragma unroll
  for (int i = 0; i < 8; i++)
    xv[i] = (float)tb[tiled_off(b, lane + 64 * i, 512)];
  float acc[8] = {0, 0, 0, 0, 0, 0, 0, 0};
#pragma unroll
  for (int i = 0; i < 8; i++) {
    const int d = lane + 64 * i;
    const float* wp = g2W + ((size_t)t * 512 + d) * 8;
    f32x4 w0 = *(const f32x4*)wp;
    f32x4 w1 = *(const f32x4*)(wp + 4);
    acc[0] += xv[i] * w0.x; acc[1] += xv[i] * w0.y;
    acc[2] += xv[i] * w0.z; acc[3] += xv[i] * w0.w;
    acc[4] += xv[i] * w1.x; acc[5] += xv[i] * w1.y;
    acc[6] += xv[i] * w1.z; acc[7] += xv[i] * w1.w;
  }
#pragma unroll
  for (int e = 0; e < 8; e++) {
#pragma unroll
    for (int off = 32; off >= 1; off >>= 1) acc[e] += __shfl_xor(acc[e], off);
    acc[e] += g2b[t * 8 + e];
  }
  float m = acc[0];
#pragma unroll
  for (int e = 1; e < 8; e++) m = fmaxf(m, acc[e]);
  float s = 0.f, p[8];
#pragma unroll
  for (int e = 0; e < 8; e++) { p[e] = expf(acc[e] - m); s += p[e]; }
  float inv = 1.0f / s;
  float mine = 0.f;
#pragma unroll
  for (int e = 0; e < 8; e++) if (lane == e) mine = p[e] * inv;
  if (lane < 8) g2[((size_t)t * Bc + b) * 8 + lane] = mine;
}

// ---------------------------------------------------------------------------
// Mix level 1 (tiled-linear): thread t8 handles 8 contiguous tiled elems
// (all same row b). E/TFh/FLh all TILED f16 -> fully coalesced 16B/lane.
// ---------------------------------------------------------------------------
__global__ __launch_bounds__(256)
void combine1_kernel(const f16* __restrict__ E, const float* __restrict__ g1,
                     const float* __restrict__ g1l, f16* __restrict__ tfh,
                     f16* __restrict__ flh, int Bc) {
  const int t8 = blockIdx.x * 256 + threadIdx.x;  // Bc*512/8
  const int b = ((t8 >> 13) << 7) | (t8 & 127);
  const size_t base = (size_t)t8 * 8;
  f16x8 ev[16];
#pragma unroll
  for (int i = 0; i < 16; i++)
    ev[i] = *(const f16x8*)(E + (size_t)i * Bc * 512 + base);
#pragma unroll
  for (int t = 0; t < 3; t++) {
    const float* g = g1 + ((size_t)t * NB + b) * 8;
    f16x8 o;
#pragma unroll
    for (int j = 0; j < 8; j++) {
      float v = g[0] * (float)ev[0][j] + g[1] * (float)ev[1][j] +
                g[2] * (float)ev[2][j] + g[3] * (float)ev[3][j];
#pragma unroll
      for (int k = 0; k < 4; k++) v += g[4 + k] * (float)ev[4 + 4 * t + k][j];
      o[j] = (f16)v;
    }
    *(f16x8*)(tfh + (size_t)t * Bc * 512 + base) = o;
  }
  const float* gl = g1l + (size_t)b * 16;
  f16x8 o;
#pragma unroll
  for (int j = 0; j < 8; j++) {
    float v = 0.f;
#pragma unroll
    for (int jj = 0; jj < 12; jj++) v += gl[jj] * (float)ev[4 + jj][j];
#pragma unroll
    for (int s2 = 0; s2 < 4; s2++) v += gl[12 + s2] * (float)ev[s2][j];
    o[j] = (f16)v;
  }
  *(f16x8*)(flh + base) = o;
}

// ---------------------------------------------------------------------------
// Mix level 2 (tiled-linear): grid (Bc/4, 3). E2/tin TILED, coalesced.
// ---------------------------------------------------------------------------
__global__ __launch_bounds__(256)
void combine2_kernel(const f16* __restrict__ E2, const float* __restrict__ g2,
                     f16* __restrict__ tin, int Bc) {
  const int t = blockIdx.y;
  const int t8 = blockIdx.x * 256 + threadIdx.x;  // Bc*512/8
  const int b = ((t8 >> 13) << 7) | (t8 & 127);
  const size_t base = (size_t)t8 * 8;
  const float* g = g2 + ((size_t)t * Bc + b) * 8;
  f16x8 es[8];
#pragma unroll
  for (int s2 = 0; s2 < 4; s2++)
    es[s2] = *(const f16x8*)(E2 + (size_t)s2 * Bc * 512 + base);
#pragma unroll
  for (int k = 0; k < 4; k++)
    es[4 + k] = *(const f16x8*)(E2 + (size_t)(4 + 4 * t + k) * Bc * 512 + base);
  f16x8 o;
#pragma unroll
  for (int j = 0; j < 8; j++) {
    float v = 0.f;
#pragma unroll
    for (int i = 0; i < 8; i++) v += g[i] * (float)es[i][j];
    o[j] = (f16)v;
  }
  *(f16x8*)(tin + (size_t)t * Bc * 512 + base) = o;
}

// ---------------------------------------------------------------------------
// churn head: TW2 tiled (Bc,256) f16 @ ch_W3 (256,1) + b -> out
// ---------------------------------------------------------------------------
__global__ __launch_bounds__(256)
void churn_l3_kernel(const f16* __restrict__ TW2, const float* __restrict__ W3,
                     const float* __restrict__ b3, float* __restrict__ out) {
  const int lane = threadIdx.x & 63;
  const int b = blockIdx.x * 4 + (threadIdx.x >> 6);
  float s = 0.f;
#pragma unroll
  for (int i = 0; i < 4; i++) {
    int d = lane + 64 * i;
    s += (float)TW2[tiled_off(b, d, 256)] * W3[d];
  }
#pragma unroll
  for (int off = 32; off >= 1; off >>= 1) s += __shfl_xor(s, off);
  if (lane == 0) out[b] = s + b3[0];
}

// ---------------------------------------------------------------------------
extern "C" void kernel_launch(void* const* d_in, const int* in_sizes, int n_in,
                              void* d_out, int out_size, void* d_ws, size_t ws_size,
                              hipStream_t stream) {
  const float* user_emb = (const float*)d_in[0];
  const float* s1_W1 = (const float*)d_in[1];
  const float* s1_b1 = (const float*)d_in[2];
  const float* s1_W2 = (const float*)d_in[3];
  const float* s1_b2 = (const float*)d_in[4];
  const float* t1_W1 = (const float*)d_in[5];
  const float* t1_b1 = (const float*)d_in[6];
  const float* t1_W2 = (const float*)d_in[7];
  const float* t1_b2 = (const float*)d_in[8];
  const float* g1_W  = (const float*)d_in[9];
  const float* g1_b  = (const float*)d_in[10];
  const float* g1l_W = (const float*)d_in[11];
  const float* g1l_b = (const float*)d_in[12];
  const float* s2_W1 = (const float*)d_in[13];
  const float* s2_b1 = (const float*)d_in[14];
  const float* s2_W2 = (const float*)d_in[15];
  const float* s2_b2 = (const float*)d_in[16];
  const float* t2_W1 = (const float*)d_in[17];
  const float* t2_b1 = (const float*)d_in[18];
  const float* t2_W2 = (const float*)d_in[19];
  const float* t2_b2 = (const float*)d_in[20];
  const float* g2_W  = (const float*)d_in[21];
  const float* g2_b  = (const float*)d_in[22];
  const float* ch_W1 = (const float*)d_in[23];
  const float* ch_b1 = (const float*)d_in[24];
  const float* ch_W2 = (const float*)d_in[25];
  const float* ch_b2 = (const float*)d_in[26];
  const float* ch_W3 = (const float*)d_in[27];
  const float* ch_b3 = (const float*)d_in[28];
  const float* bt_W1 = (const float*)d_in[29];
  const float* bt_b1 = (const float*)d_in[30];
  const float* bt_W2 = (const float*)d_in[31];
  const float* bt_b2 = (const float*)d_in[32];
  const float* bt_W3 = (const float*)d_in[33];
  const float* bt_b3 = (const float*)d_in[34];

  // ---- workspace plan: persistent + per-chunk, Bc chosen from ws_size ----
  const size_t PERSIST = 74800000ull;          // ~74.8 MB incl. padding
  const size_t PERCHUNK_PER_ROW = 61024ull;    // bytes per batch row
  int Bc = 4096;
  while (Bc > 256 &&
         PERSIST + PERCHUNK_PER_ROW * (size_t)Bc + (64ull << 10) > ws_size)
    Bc >>= 1;
  const int nchunks = NB / Bc;

  char* w = (char*)d_ws;
  auto alloc = [&](size_t bytes) {
    char* p = w;
    w += (bytes + 255) & ~(size_t)255;
    return p;
  };
  // persistent (weights tiled)
  f16* WT1 = (f16*)alloc(16ull * 512 * 1024 * 2);
  f16* WT2 = (f16*)alloc(16ull * 1024 * 512 * 2);
  f16* WT3 = (f16*)alloc(16ull * 512 * 1024 * 2);
  f16* WT4 = (f16*)alloc(16ull * 1024 * 512 * 2);
  f16* WT5 = (f16*)alloc(3ull * 512 * 512 * 2);
  f16* WT6 = (f16*)alloc(3ull * 256 * 512 * 2);
  f16* WT7 = (f16*)alloc(2ull * 128 * 256 * 2);  // padded to 128 rows, zeroed
  f16* Uemb = (f16*)alloc((size_t)NB * 512 * 2); // tiled
  float* B1  = (float*)alloc(16384 * 4);
  float* B2  = (float*)alloc(8192 * 4);
  float* B3  = (float*)alloc(16384 * 4);
  float* B4  = (float*)alloc(8192 * 4);
  float* BT1 = (float*)alloc(1536 * 4);
  float* BT2 = (float*)alloc(768 * 4);
  float* G1  = (float*)alloc(3ull * NB * 8 * 4);
  float* G1L = (float*)alloc((size_t)NB * 16 * 4);
  // per-chunk
  f16*   Hc   = (f16*)alloc(16ull * Bc * 1024 * 2);  // tiled
  f16*   Ec   = (f16*)alloc(16ull * Bc * 512 * 2);   // tiled
  f16*   TFh  = (f16*)alloc(3ull * Bc * 512 * 2);    // tiled
  f16*   FLh  = (f16*)alloc((size_t)Bc * 512 * 2);   // tiled
  float* G2c  = (float*)alloc(3ull * Bc * 8 * 4);
  f16*   TINc = (f16*)alloc(3ull * Bc * 512 * 2);    // tiled
  f16*   TW1c = (f16*)alloc(3ull * Bc * 512 * 2);    // tiled
  f16*   TW2c = (f16*)alloc(3ull * Bc * 256 * 2);    // tiled
  if ((size_t)(w - (char*)d_ws) > ws_size) return;  // truly too small

  // ---- bias packing + WT7 zero: one kernel ----
  pack_kernel<<<329, 256, 0, stream>>>(B1, s1_b1, t1_b1, B2, s1_b2, t1_b2,
                                       B3, s2_b1, t2_b1, B4, s2_b2, t2_b2,
                                       BT1, ch_b1, bt_b1, BT2, ch_b2, bt_b2,
                                       (uint32_t*)WT7);

  // ---- ALL weight transposes: one grid-stride dispatch, no LDS, x4 vec ----
  {
    TAll ta;
    int acc_wv = 0;
    auto set = [&](int i, const float* sA, int nA, const float* sB, f16* dst,
                   int K, int N, int dstStride, int nz) {
      const int wx = (N + 255) >> 8;
      acc_wv += wx * (K >> 3) * nz;
      ta.s[i] = TSet{sA, sB, dst, nA, K, N, wx, dstStride, acc_wv};
    };
    set(0, s1_W1, 4, t1_W1, WT1, 512, 1024, 512 * 1024, 16);
    set(1, s1_W2, 4, t1_W2, WT2, 1024, 512, 1024 * 512, 16);
    set(2, s2_W1, 4, t2_W1, WT3, 512, 1024, 512 * 1024, 16);
    set(3, s2_W2, 4, t2_W2, WT4, 1024, 512, 1024 * 512, 16);
    set(4, ch_W1, 1, bt_W1, WT5, 512, 512, 512 * 512, 3);
    set(5, ch_W2, 1, bt_W2, WT6, 512, 256, 256 * 512, 3);
    set(6, bt_W3, 2, nullptr, WT7, 256, 100, 128 * 256, 2);
    const int nblk = (acc_wv + 3) / 4 < 2048 ? (acc_wv + 3) / 4 : 2048;
    transpose_all_kernel<<<nblk, 256, 0, stream>>>(ta, acc_wv);
  }
  cvt_kernel<<<2048, 256, 0, stream>>>(user_emb, Uemb, NB * 512 / 4);
  gates1_kernel<<<NB / 4, 256, 0, stream>>>(user_emb, g1_W, g1_b, g1l_W, g1l_b, G1, G1L);

  GemmArgs ga;
  const int MB = Bc / 128;  // grid.y

  for (int c = 0; c < nchunks; ++c) {
    const int b0 = c * Bc;

    // stage 1a: 16 experts (Bc,512)x(512,1024), relu, f16 tiled -> Hc
    ga.N = 1024; ga.K = 512;
    for (int g = 0; g < 16; g++) {
      ga.A[g] = Uemb + (size_t)b0 * 512;
      ga.W[g] = WT1 + (size_t)g * 512 * 1024;
      ga.bias[g] = B1 + g * 1024;
      ga.C[g] = Hc + (size_t)g * Bc * 1024;
    }
    gemm_kernel<true, 2><<<dim3(8, MB, 16), 256, 0, stream>>>(ga);

    // stage 1b: 16 experts (Bc,1024)x(1024,512), f16 tiled -> Ec
    ga.N = 512; ga.K = 1024;
    for (int g = 0; g < 16; g++) {
      ga.A[g] = Hc + (size_t)g * Bc * 1024;
      ga.W[g] = WT2 + (size_t)g * 1024 * 512;
      ga.bias[g] = B2 + g * 512;
      ga.C[g] = Ec + (size_t)g * Bc * 512;
    }
    gemm_kernel<false, 2><<<dim3(4, MB, 16), 256, 0, stream>>>(ga);

    combine1_kernel<<<Bc / 4, 256, 0, stream>>>(
        Ec, G1 + (size_t)b0 * 8, G1L + (size_t)b0 * 16, TFh, FLh, Bc);
    gates2_kernel<<<dim3(Bc / 4, 3), 256, 0, stream>>>(TFh, g2_W, g2_b, G2c, Bc);

    // stage 2a
    ga.N = 1024; ga.K = 512;
    for (int g = 0; g < 16; g++) {
      ga.A[g] = (g < 4) ? FLh : TFh + (size_t)((g - 4) >> 2) * Bc * 512;
      ga.W[g] = WT3 + (size_t)g * 512 * 1024;
      ga.bias[g] = B3 + g * 1024;
      ga.C[g] = Hc + (size_t)g * Bc * 1024;
    }
    gemm_kernel<true, 2><<<dim3(8, MB, 16), 256, 0, stream>>>(ga);

    // stage 2b
    ga.N = 512; ga.K = 1024;
    for (int g = 0; g < 16; g++) {
      ga.A[g] = Hc + (size_t)g * Bc * 1024;
      ga.W[g] = WT4 + (size_t)g * 1024 * 512;
      ga.bias[g] = B4 + g * 512;
      ga.C[g] = Ec + (size_t)g * Bc * 512;
    }
    gemm_kernel<false, 2><<<dim3(4, MB, 16), 256, 0, stream>>>(ga);

    combine2_kernel<<<dim3(Bc / 4, 3), 256, 0, stream>>>(Ec, G2c, TINc, Bc);

    // towers L1: 3 groups (Bc,512)x(512,512) relu -> TW1c tiled
    ga.N = 512; ga.K = 512;
    for (int g = 0; g < 3; g++) {
      ga.A[g] = TINc + (size_t)g * Bc * 512;
      ga.W[g] = WT5 + (size_t)g * 512 * 512;
      ga.bias[g] = BT1 + g * 512;
      ga.C[g] = TW1c + (size_t)g * Bc * 512;
    }
    for (int g = 3; g < 16; g++) { ga.A[g] = ga.A[0]; ga.W[g] = ga.W[0]; ga.bias[g] = ga.bias[0]; ga.C[g] = ga.C[0]; }
    gemm_kernel<true, 2><<<dim3(4, MB, 3), 256, 0, stream>>>(ga);

    // towers L2: 3 groups (Bc,512)x(512,256) relu -> TW2c tiled
    ga.N = 256; ga.K = 512;
    for (int g = 0; g < 3; g++) {
      ga.A[g] = TW1c + (size_t)g * Bc * 512;
      ga.W[g] = WT6 + (size_t)g * 256 * 512;
      ga.bias[g] = BT2 + g * 256;
      ga.C[g] = TW2c + (size_t)g * Bc * 256;
    }
    for (int g = 3; g < 16; g++) { ga.A[g] = ga.A[0]; ga.W[g] = ga.W[0]; ga.bias[g] = ga.bias[0]; ga.C[g] = ga.C[0]; }
    gemm_kernel<true, 2><<<dim3(2, MB, 3), 256, 0, stream>>>(ga);

    churn_l3_kernel<<<Bc / 4, 256, 0, stream>>>(TW2c, ch_W3, ch_b3,
                                                (float*)d_out + b0);

    // bt heads: 2 groups (Bc,256)x(256,100 padded 128) -> d_out f32 row-major
    ga.N = 100; ga.K = 256;
    for (int g = 0; g < 2; g++) {
      ga.A[g] = TW2c + (size_t)(1 + g) * Bc * 256;
      ga.W[g] = WT7 + (size_t)g * 128 * 256;
      ga.bias[g] = bt_b3 + g * 100;
      ga.C[g] = (float*)d_out + NB + (size_t)g * NB * 100 + (size_t)b0 * 100;
    }
    for (int g = 2; g < 16; g++) { ga.A[g] = ga.A[0]; ga.W[g] = ga.W[0]; ga.bias[g] = ga.bias[0]; ga.C[g] = ga.C[0]; }
    gemm_kernel<false, 0><<<dim3(1, MB, 2), 256, 0, stream>>>(ga);
  }
}

// Round 15
// 482.408 us; speedup vs baseline: 1.0149x; 1.0149x over previous
//
#include <hip/hip_runtime.h>
#include <stdint.h>
#include <stddef.h>

typedef float f32x4 __attribute__((ext_vector_type(4)));
typedef int   i32x4 __attribute__((ext_vector_type(4)));
typedef _Float16 f16;
typedef _Float16 f16x8 __attribute__((ext_vector_type(8)));
typedef _Float16 f16x4 __attribute__((ext_vector_type(4)));

#define NB 4096  // batch

// Tiled operand layout (= LDS tile order): 128-row M-tiles, BK=32 K-blocks,
// within block: [kq(4)][row(128)][8 f16]. One wave stages 1KB contiguous;
// a 128x128 tile (4 K-blocks) is one contiguous 32KB region.
__device__ __forceinline__ size_t tiled_off(int m, int k, int K) {
  return (size_t)(m >> 7) * ((size_t)128 * K) + (size_t)(k >> 5) * 4096 +
         (size_t)(((k >> 3) & 3) * 1024 + (m & 127) * 8 + (k & 7));
}

// async global->LDS, 16B per lane, wave-uniform LDS base + lane*16
__device__ __forceinline__ void gload_lds16(const f16* g, f16* l) {
  __builtin_amdgcn_global_load_lds(
      (const __attribute__((address_space(1))) void*)g,
      (__attribute__((address_space(3))) void*)l, 16, 0, 0);
}

struct GemmArgs {
  const f16* A[16];
  const f16* W[16];
  const float* bias[16];
  void* C[16];
  int N, K;
};

// ---------------------------------------------------------------------------
// 128x128 2-phase kernel, BK=32 (r10-proven: 45.7us/dispatch, ~755 TF).
// 256 thr (4 waves 2x2), 32KB LDS (As 2-buf | Bs 2-buf, aliased with C
// bounce), global_load_lds staging, __syncthreads double-buffer. Bounce-store
// per-lane-constant XOR swizzle -> conflict-free (r10: SQ_LDS_BANK_CONFLICT=0).
// OMODE: 0 = f32 row-major (guarded), 2 = f16 tiled.
// ---------------------------------------------------------------------------
template<bool RELU, int OMODE>
__global__ __launch_bounds__(256, 4)
void gemm_kernel(GemmArgs args) {
  // XCD-aware bijective block swizzle (all grids here have nwg % 8 == 0)
  const int nwg = gridDim.x * gridDim.y * gridDim.z;
  int bid = blockIdx.x + gridDim.x * (blockIdx.y + gridDim.y * blockIdx.z);
  if ((nwg & 7) == 0) {
    const int cpx = nwg >> 3;
    bid = (bid & 7) * cpx + (bid >> 3);
  }
  const int gx  = bid % gridDim.x;
  const int rem = bid / gridDim.x;
  const int gy  = rem % gridDim.y;
  const int g   = rem / gridDim.y;
  const int n0 = gx * 128, m0 = gy * 128;

  const int tid = threadIdx.x;
  const int lane = tid & 63;
  const int wid = tid >> 6;
  const int wr = wid >> 1, wc = wid & 1;
  const int N = args.N, K = args.K;

  // SH[0..8191] = As (2 bufs x 4096), SH[8192..16383] = Bs; reused as C bounce
  __shared__ __align__(16) f16 SH[16384];

  const f16* __restrict__ At = args.A[g] + (size_t)gy * 128 * K;
  const f16* __restrict__ Wt = args.W[g] + (size_t)gx * 128 * K;

  const int e0 = tid * 8, e1 = e0 + 2048;
  const int wb0 = (tid & ~63) * 8;
  const int wb1 = wb0 + 2048;

  f32x4 acc[4][4];
#pragma unroll
  for (int i = 0; i < 4; i++)
#pragma unroll
    for (int j = 0; j < 4; j++) { f32x4 z = {0.f, 0.f, 0.f, 0.f}; acc[i][j] = z; }

  const int nsteps = K >> 5;

  {
    f16* ab = SH;          // As buf 0
    f16* bb = SH + 8192;   // Bs buf 0
    gload_lds16(At + e0, ab + wb0);
    gload_lds16(At + e1, ab + wb1);
    gload_lds16(Wt + e0, bb + wb0);
    gload_lds16(Wt + e1, bb + wb1);
  }
  __syncthreads();

  for (int s = 0; s < nsteps; ++s) {
    const int cur = s & 1;
    if (s + 1 < nsteps) {
      const int nxt = cur ^ 1;
      const int off = (s + 1) << 12;
      f16* ab = SH + nxt * 4096;
      f16* bb = SH + 8192 + nxt * 4096;
      gload_lds16(At + off + e0, ab + wb0);
      gload_lds16(At + off + e1, ab + wb1);
      gload_lds16(Wt + off + e0, bb + wb0);
      gload_lds16(Wt + off + e1, bb + wb1);
    }
    const f16* ab = SH + cur * 4096;
    const f16* bb = SH + 8192 + cur * 4096;
    f16x8 af[4], bfv[4];
#pragma unroll
    for (int i = 0; i < 4; i++)
      af[i] = *(const f16x8*)(ab + (lane >> 4) * 1024 + (wr * 64 + i * 16 + (lane & 15)) * 8);
#pragma unroll
    for (int j = 0; j < 4; j++)
      bfv[j] = *(const f16x8*)(bb + (lane >> 4) * 1024 + (wc * 64 + j * 16 + (lane & 15)) * 8);
#pragma unroll
    for (int i = 0; i < 4; i++)
#pragma unroll
      for (int j = 0; j < 4; j++)
        acc[i][j] = __builtin_amdgcn_mfma_f32_16x16x32_f16(af[i], bfv[j], acc[i][j], 0, 0, 0);
    if (s + 1 < nsteps) __syncthreads();  // next buffer staged; cur reads done
  }

  const float* __restrict__ bias = args.bias[g];

  if constexpr (OMODE == 2) {
    // coalesced epilogue: bounce C-tile through LDS (tile is contiguous 32KB)
    // store-side swizzle: per-lane constant (bits 3,4) -> conflict-free
    __syncthreads();  // all LDS reads of the main loop complete
    const int swz = (((lane >> 3) & 1) << 3) | (((lane >> 5) & 1) << 4);
#pragma unroll
    for (int j = 0; j < 4; j++) {
      const int col = wc * 64 + j * 16 + (lane & 15);
      const float bv = bias[n0 + col];
#pragma unroll
      for (int i = 0; i < 4; i++) {
        const int rowb = wr * 64 + i * 16 + ((lane >> 4) << 2);
#pragma unroll
        for (int q = 0; q < 4; q++) {
          float v = acc[i][j][q] + bv;
          if (RELU) v = fmaxf(v, 0.0f);
          SH[tiled_off(rowb + q, col, 128) ^ swz] = (f16)v;
        }
      }
    }
    __syncthreads();
    f16* __restrict__ Cg = (f16*)args.C[g] + ((size_t)gy * N + n0) * 128;
#pragma unroll
    for (int r = 0; r < 8; r++) {
      const int c = r * 256 + tid;
      const int te = (c * 8) ^ (((c >> 7) & 1) << 3) ^ (((c >> 3) & 1) << 4);
      i32x4 v = *(const i32x4*)(SH + te);
      *(i32x4*)(Cg + (size_t)c * 8) = v;
    }
  } else {
    // f32 row-major, N-guarded scalar epilogue (heads only)
#pragma unroll
    for (int j = 0; j < 4; j++) {
      const int n = n0 + wc * 64 + j * 16 + (lane & 15);
      if (n < N) {
        const float bv = bias[n];
#pragma unroll
        for (int i = 0; i < 4; i++) {
          const int mrow = m0 + wr * 64 + i * 16 + ((lane >> 4) << 2);
#pragma unroll
          for (int q = 0; q < 4; q++) {
            float v = acc[i][j][q] + bv;
            if (RELU) v = fmaxf(v, 0.0f);
            ((float*)args.C[g])[(size_t)(mrow + q) * N + n] = v;
          }
        }
      }
    }
  }
}

// ---------------------------------------------------------------------------
// ALL weight transposes in ONE dispatch, NO LDS (r13-proven: 53us, 0 confl):
// one wave per (64-col x 8-row) subtile. Lane n: 8 scalar f32 loads down
// column (each a 256B coalesced wave-segment), cvt, one f16x8 tiled store
// (contiguous 1KB wave-store). Descriptor table, explicit dstStride.
// ---------------------------------------------------------------------------
struct TSet {
  const float* srcA;
  const float* srcB;
  f16* dst;
  int nA, K, N, wx, dstStride, wvEnd;  // wx = ceil(N/64); wvEnd cumulative
};
struct TAll { TSet s[7]; };

__global__ __launch_bounds__(256)
void transpose_all_kernel(TAll args) {
  const int wv = blockIdx.x * 4 + (threadIdx.x >> 6);
  const int lane = threadIdx.x & 63;
  int si = 0;
#pragma unroll
  for (int i = 0; i < 7; i++) si += (wv >= args.s[i].wvEnd) ? 1 : 0;
  if (si >= 7) return;  // tail waves
  const TSet S = args.s[si];
  const int local = wv - (si ? args.s[si - 1].wvEnd : 0);
  const int perz = S.wx * (S.K >> 3);
  const int z = local / perz;
  const int r = local - z * perz;
  const int ko = r / S.wx;                 // k-oct index
  const int n = (r - ko * S.wx) * 64 + lane;
  const int K = S.K, N = S.N;
  const float* __restrict__ src =
      (z < S.nA) ? S.srcA + (size_t)z * K * N : S.srcB + (size_t)(z - S.nA) * K * N;
  if (n < N) {
    const int kbase = ko * 8;
    f16x8 o;
#pragma unroll
    for (int e = 0; e < 8; e++)
      o[e] = (f16)src[(size_t)(kbase + e) * N + n];
    *(f16x8*)(S.dst + (size_t)z * S.dstStride + tiled_off(n, kbase, K)) = o;
  }
}

// user_emb f32 row-major -> Uemb f16 tiled (K=512)
__global__ __launch_bounds__(256)
void cvt_kernel(const float* __restrict__ src, f16* __restrict__ dst, int n4) {
  int i = blockIdx.x * 256 + threadIdx.x;
  if (i < n4) {
    f32x4 v = *(const f32x4*)(src + (size_t)i * 4);
    f16x4 o = {(f16)v.x, (f16)v.y, (f16)v.z, (f16)v.w};
    const int e = i * 4;
    *(f16x4*)(dst + tiled_off(e >> 9, e & 511, 512)) = o;
  }
}

// ---------------------------------------------------------------------------
// bias packing + WT7 zeroing, one kernel
// ---------------------------------------------------------------------------
__global__ __launch_bounds__(256)
void pack_kernel(float* B1, const float* s1b1, const float* t1b1,
                 float* B2, const float* s1b2, const float* t1b2,
                 float* B3, const float* s2b1, const float* t2b1,
                 float* B4, const float* s2b2, const float* t2b2,
                 float* BT1, const float* chb1, const float* btb1,
                 float* BT2, const float* chb2, const float* btb2,
                 uint32_t* wt7z) {
  int i = blockIdx.x * 256 + threadIdx.x;
  if (i < 16384) { B1[i] = (i < 4096) ? s1b1[i] : t1b1[i - 4096]; return; }
  i -= 16384;
  if (i < 8192)  { B2[i] = (i < 2048) ? s1b2[i] : t1b2[i - 2048]; return; }
  i -= 8192;
  if (i < 16384) { B3[i] = (i < 4096) ? s2b1[i] : t2b1[i - 4096]; return; }
  i -= 16384;
  if (i < 8192)  { B4[i] = (i < 2048) ? s2b2[i] : t2b2[i - 2048]; return; }
  i -= 8192;
  if (i < 1536)  { BT1[i] = (i < 512) ? chb1[i] : btb1[i - 512]; return; }
  i -= 1536;
  if (i < 768)   { BT2[i] = (i < 256) ? chb2[i] : btb2[i - 256]; return; }
  i -= 768;
  if (i < 32768) wt7z[i] = 0u;
}

// ---------------------------------------------------------------------------
// Gates level 1 (full batch)
// ---------------------------------------------------------------------------
__global__ __launch_bounds__(256)
void gates1_kernel(const float* __restrict__ x, const float* __restrict__ g1W,
                   const float* __restrict__ g1b, const float* __restrict__ g1lW,
                   const float* __restrict__ g1lb, float* __restrict__ g1,
                   float* __restrict__ g1l) {
  const int lane = threadIdx.x & 63;
  const int b = blockIdx.x * 4 + (threadIdx.x >> 6);
  float xv[8];
#pragma unroll
  for (int i = 0; i < 8; i++) xv[i] = x[(size_t)b * 512 + lane + 64 * i];

#pragma unroll
  for (int t = 0; t < 3; t++) {
    float acc[8] = {0, 0, 0, 0, 0, 0, 0, 0};
#pragma unroll
    for (int i = 0; i < 8; i++) {
      const int d = lane + 64 * i;
      const float* wp = g1W + ((size_t)t * 512 + d) * 8;
      f32x4 w0 = *(const f32x4*)wp;
      f32x4 w1 = *(const f32x4*)(wp + 4);
      acc[0] += xv[i] * w0.x; acc[1] += xv[i] * w0.y;
      acc[2] += xv[i] * w0.z; acc[3] += xv[i] * w0.w;
      acc[4] += xv[i] * w1.x; acc[5] += xv[i] * w1.y;
      acc[6] += xv[i] * w1.z; acc[7] += xv[i] * w1.w;
    }
#pragma unroll
    for (int e = 0; e < 8; e++) {
#pragma unroll
      for (int off = 32; off >= 1; off >>= 1) acc[e] += __shfl_xor(acc[e], off);
      acc[e] += g1b[t * 8 + e];
    }
    float m = acc[0];
#pragma unroll
    for (int e = 1; e < 8; e++) m = fmaxf(m, acc[e]);
    float s = 0.f, p[8];
#pragma unroll
    for (int e = 0; e < 8; e++) { p[e] = expf(acc[e] - m); s += p[e]; }
    float inv = 1.0f / s;
    float mine = 0.f;
#pragma unroll
    for (int e = 0; e < 8; e++) if (lane == e) mine = p[e] * inv;
    if (lane < 8) g1[((size_t)t * NB + b) * 8 + lane] = mine;
  }

  float acc[16] = {};
#pragma unroll
  for (int i = 0; i < 8; i++) {
    const int d = lane + 64 * i;
    const float* wp = g1lW + (size_t)d * 16;
#pragma unroll
    for (int e4 = 0; e4 < 4; e4++) {
      f32x4 wv = *(const f32x4*)(wp + e4 * 4);
      acc[e4 * 4 + 0] += xv[i] * wv.x; acc[e4 * 4 + 1] += xv[i] * wv.y;
      acc[e4 * 4 + 2] += xv[i] * wv.z; acc[e4 * 4 + 3] += xv[i] * wv.w;
    }
  }
#pragma unroll
  for (int e = 0; e < 16; e++) {
#pragma unroll
    for (int off = 32; off >= 1; off >>= 1) acc[e] += __shfl_xor(acc[e], off);
    acc[e] += g1lb[e];
  }
  float m = acc[0];
#pragma unroll
  for (int e = 1; e < 16; e++) m = fmaxf(m, acc[e]);
  float s = 0.f, p[16];
#pragma unroll
  for (int e = 0; e < 16; e++) { p[e] = expf(acc[e] - m); s += p[e]; }
  float inv = 1.0f / s;
  float mine = 0.f;
#pragma unroll
  for (int e = 0; e < 16; e++) if (lane == e) mine = p[e] * inv;
  if (lane < 16) g1l[(size_t)b * 16 + lane] = mine;
}

// ---------------------------------------------------------------------------
// Gates level 2 (chunked): grid (Bc/4, 3). tf (3,Bc-tiled,512) f16.
// ---------------------------------------------------------------------------
__global__ __launch_bounds__(256)
void gates2_kernel(const f16* __restrict__ tf, const float* __restrict__ g2W,
                   const float* __restrict__ g2b, float* __restrict__ g2, int Bc) {
  const int lane = threadIdx.x & 63;
  const int b = blockIdx.x * 4 + (threadIdx.x >> 6);
  const int t = blockIdx.y;
  const f16* tb = tf + (size_t)t * Bc * 512;
  float xv[8];
#pragma unroll
  for (int i = 0; i < 8; i++)
    xv[i] = (float)tb[tiled_off(b, lane + 64 * i, 512)];
  float acc[8] = {0, 0, 0, 0, 0, 0, 0, 0};
#pragma unroll
  for (int i = 0; i < 8; i++) {
    const int d = lane + 64 * i;
    const float* wp = g2W + ((size_t)t * 512 + d) * 8;
    f32x4 w0 = *(const f32x4*)wp;
    f32x4 w1 = *(const f32x4*)(wp + 4);
    acc[0] += xv[i] * w0.x; acc[1] += xv[i] * w0.y;
    acc[2] += xv[i] * w0.z; acc[3] += xv[i] * w0.w;
    acc[4] += xv[i] * w1.x; acc[5] += xv[i] * w1.y;
    acc[6] += xv[i] * w1.z; acc[7] += xv[i] * w1.w;
  }
#pragma unroll
  for (int e = 0; e < 8; e++) {
#pragma unroll
    for (int off = 32; off >= 1; off >>= 1) acc[e] += __shfl_xor(acc[e], off);
    acc[e] += g2b[t * 8 + e];
  }
  float m = acc[0];
#pragma unroll
  for (int e = 1; e < 8; e++) m = fmaxf(m, acc[e]);
  float s = 0.f, p[8];
#pragma unroll
  for (int e = 0; e < 8; e++) { p[e] = expf(acc[e] - m); s += p[e]; }
  float inv = 1.0f / s;
  float mine = 0.f;
#pragma unroll
  for (int e = 0; e < 8; e++) if (lane == e) mine = p[e] * inv;
  if (lane < 8) g2[((size_t)t * Bc + b) * 8 + lane] = mine;
}

// ---------------------------------------------------------------------------
// Mix level 1 (tiled-linear): thread t8 handles 8 contiguous tiled elems
// (all same row b). E/TFh/FLh all TILED f16 -> fully coalesced 16B/lane.
// ---------------------------------------------------------------------------
__global__ __launch_bounds__(256)
void combine1_kernel(const f16* __restrict__ E, const float* __restrict__ g1,
                     const float* __restrict__ g1l, f16* __restrict__ tfh,
                     f16* __restrict__ flh, int Bc) {
  const int t8 = blockIdx.x * 256 + threadIdx.x;  // Bc*512/8
  const int b = ((t8 >> 13) << 7) | (t8 & 127);
  const size_t base = (size_t)t8 * 8;
  f16x8 ev[16];
#pragma unroll
  for (int i = 0; i < 16; i++)
    ev[i] = *(const f16x8*)(E + (size_t)i * Bc * 512 + base);
#pragma unroll
  for (int t = 0; t < 3; t++) {
    const float* g = g1 + ((size_t)t * NB + b) * 8;
    f16x8 o;
#pragma unroll
    for (int j = 0; j < 8; j++) {
      float v = g[0] * (float)ev[0][j] + g[1] * (float)ev[1][j] +
                g[2] * (float)ev[2][j] + g[3] * (float)ev[3][j];
#pragma unroll
      for (int k = 0; k < 4; k++) v += g[4 + k] * (float)ev[4 + 4 * t + k][j];
      o[j] = (f16)v;
    }
    *(f16x8*)(tfh + (size_t)t * Bc * 512 + base) = o;
  }
  const float* gl = g1l + (size_t)b * 16;
  f16x8 o;
#pragma unroll
  for (int j = 0; j < 8; j++) {
    float v = 0.f;
#pragma unroll
    for (int jj = 0; jj < 12; jj++) v += gl[jj] * (float)ev[4 + jj][j];
#pragma unroll
    for (int s2 = 0; s2 < 4; s2++) v += gl[12 + s2] * (float)ev[s2][j];
    o[j] = (f16)v;
  }
  *(f16x8*)(flh + base) = o;
}

// ---------------------------------------------------------------------------
// Mix level 2 (tiled-linear): grid (Bc/4, 3). E2/tin TILED, coalesced.
// ---------------------------------------------------------------------------
__global__ __launch_bounds__(256)
void combine2_kernel(const f16* __restrict__ E2, const float* __restrict__ g2,
                     f16* __restrict__ tin, int Bc) {
  const int t = blockIdx.y;
  const int t8 = blockIdx.x * 256 + threadIdx.x;  // Bc*512/8
  const int b = ((t8 >> 13) << 7) | (t8 & 127);
  const size_t base = (size_t)t8 * 8;
  const float* g = g2 + ((size_t)t * Bc + b) * 8;
  f16x8 es[8];
#pragma unroll
  for (int s2 = 0; s2 < 4; s2++)
    es[s2] = *(const f16x8*)(E2 + (size_t)s2 * Bc * 512 + base);
#pragma unroll
  for (int k = 0; k < 4; k++)
    es[4 + k] = *(const f16x8*)(E2 + (size_t)(4 + 4 * t + k) * Bc * 512 + base);
  f16x8 o;
#pragma unroll
  for (int j = 0; j < 8; j++) {
    float v = 0.f;
#pragma unroll
    for (int i = 0; i < 8; i++) v += g[i] * (float)es[i][j];
    o[j] = (f16)v;
  }
  *(f16x8*)(tin + (size_t)t * Bc * 512 + base) = o;
}

// ---------------------------------------------------------------------------
// churn head: TW2 tiled (Bc,256) f16 @ ch_W3 (256,1) + b -> out
// ---------------------------------------------------------------------------
__global__ __launch_bounds__(256)
void churn_l3_kernel(const f16* __restrict__ TW2, const float* __restrict__ W3,
                     const float* __restrict__ b3, float* __restrict__ out) {
  const int lane = threadIdx.x & 63;
  const int b = blockIdx.x * 4 + (threadIdx.x >> 6);
  float s = 0.f;
#pragma unroll
  for (int i = 0; i < 4; i++) {
    int d = lane + 64 * i;
    s += (float)TW2[tiled_off(b, d, 256)] * W3[d];
  }
#pragma unroll
  for (int off = 32; off >= 1; off >>= 1) s += __shfl_xor(s, off);
  if (lane == 0) out[b] = s + b3[0];
}

// ---------------------------------------------------------------------------
extern "C" void kernel_launch(void* const* d_in, const int* in_sizes, int n_in,
                              void* d_out, int out_size, void* d_ws, size_t ws_size,
                              hipStream_t stream) {
  const float* user_emb = (const float*)d_in[0];
  const float* s1_W1 = (const float*)d_in[1];
  const float* s1_b1 = (const float*)d_in[2];
  const float* s1_W2 = (const float*)d_in[3];
  const float* s1_b2 = (const float*)d_in[4];
  const float* t1_W1 = (const float*)d_in[5];
  const float* t1_b1 = (const float*)d_in[6];
  const float* t1_W2 = (const float*)d_in[7];
  const float* t1_b2 = (const float*)d_in[8];
  const float* g1_W  = (const float*)d_in[9];
  const float* g1_b  = (const float*)d_in[10];
  const float* g1l_W = (const float*)d_in[11];
  const float* g1l_b = (const float*)d_in[12];
  const float* s2_W1 = (const float*)d_in[13];
  const float* s2_b1 = (const float*)d_in[14];
  const float* s2_W2 = (const float*)d_in[15];
  const float* s2_b2 = (const float*)d_in[16];
  const float* t2_W1 = (const float*)d_in[17];
  const float* t2_b1 = (const float*)d_in[18];
  const float* t2_W2 = (const float*)d_in[19];
  const float* t2_b2 = (const float*)d_in[20];
  const float* g2_W  = (const float*)d_in[21];
  const float* g2_b  = (const float*)d_in[22];
  const float* ch_W1 = (const float*)d_in[23];
  const float* ch_b1 = (const float*)d_in[24];
  const float* ch_W2 = (const float*)d_in[25];
  const float* ch_b2 = (const float*)d_in[26];
  const float* ch_W3 = (const float*)d_in[27];
  const float* ch_b3 = (const float*)d_in[28];
  const float* bt_W1 = (const float*)d_in[29];
  const float* bt_b1 = (const float*)d_in[30];
  const float* bt_W2 = (const float*)d_in[31];
  const float* bt_b2 = (const float*)d_in[32];
  const float* bt_W3 = (const float*)d_in[33];
  const float* bt_b3 = (const float*)d_in[34];

  // ---- workspace plan: persistent + per-chunk, Bc chosen from ws_size ----
  const size_t PERSIST = 74800000ull;          // ~74.8 MB incl. padding
  const size_t PERCHUNK_PER_ROW = 61024ull;    // bytes per batch row
  int Bc = 4096;
  while (Bc > 256 &&
         PERSIST + PERCHUNK_PER_ROW * (size_t)Bc + (64ull << 10) > ws_size)
    Bc >>= 1;
  const int nchunks = NB / Bc;

  char* w = (char*)d_ws;
  auto alloc = [&](size_t bytes) {
    char* p = w;
    w += (bytes + 255) & ~(size_t)255;
    return p;
  };
  // persistent (weights tiled)
  f16* WT1 = (f16*)alloc(16ull * 512 * 1024 * 2);
  f16* WT2 = (f16*)alloc(16ull * 1024 * 512 * 2);
  f16* WT3 = (f16*)alloc(16ull * 512 * 1024 * 2);
  f16* WT4 = (f16*)alloc(16ull * 1024 * 512 * 2);
  f16* WT5 = (f16*)alloc(3ull * 512 * 512 * 2);
  f16* WT6 = (f16*)alloc(3ull * 256 * 512 * 2);
  f16* WT7 = (f16*)alloc(2ull * 128 * 256 * 2);  // padded to 128 rows, zeroed
  f16* Uemb = (f16*)alloc((size_t)NB * 512 * 2); // tiled
  float* B1  = (float*)alloc(16384 * 4);
  float* B2  = (float*)alloc(8192 * 4);
  float* B3  = (float*)alloc(16384 * 4);
  float* B4  = (float*)alloc(8192 * 4);
  float* BT1 = (float*)alloc(1536 * 4);
  float* BT2 = (float*)alloc(768 * 4);
  float* G1  = (float*)alloc(3ull * NB * 8 * 4);
  float* G1L = (float*)alloc((size_t)NB * 16 * 4);
  // per-chunk
  f16*   Hc   = (f16*)alloc(16ull * Bc * 1024 * 2);  // tiled
  f16*   Ec   = (f16*)alloc(16ull * Bc * 512 * 2);   // tiled
  f16*   TFh  = (f16*)alloc(3ull * Bc * 512 * 2);    // tiled
  f16*   FLh  = (f16*)alloc((size_t)Bc * 512 * 2);   // tiled
  float* G2c  = (float*)alloc(3ull * Bc * 8 * 4);
  f16*   TINc = (f16*)alloc(3ull * Bc * 512 * 2);    // tiled
  f16*   TW1c = (f16*)alloc(3ull * Bc * 512 * 2);    // tiled
  f16*   TW2c = (f16*)alloc(3ull * Bc * 256 * 2);    // tiled
  if ((size_t)(w - (char*)d_ws) > ws_size) return;  // truly too small

  // ---- bias packing + WT7 zero: one kernel ----
  pack_kernel<<<329, 256, 0, stream>>>(B1, s1_b1, t1_b1, B2, s1_b2, t1_b2,
                                       B3, s2_b1, t2_b1, B4, s2_b2, t2_b2,
                                       BT1, ch_b1, bt_b1, BT2, ch_b2, bt_b2,
                                       (uint32_t*)WT7);

  // ---- ALL weight transposes: one dispatch, no LDS (r13 version) ----
  {
    TAll ta;
    int acc_wv = 0;
    auto set = [&](int i, const float* sA, int nA, const float* sB, f16* dst,
                   int K, int N, int dstStride, int nz) {
      const int wx = (N + 63) >> 6;
      acc_wv += wx * (K >> 3) * nz;
      ta.s[i] = TSet{sA, sB, dst, nA, K, N, wx, dstStride, acc_wv};
    };
    set(0, s1_W1, 4, t1_W1, WT1, 512, 1024, 512 * 1024, 16);
    set(1, s1_W2, 4, t1_W2, WT2, 1024, 512, 1024 * 512, 16);
    set(2, s2_W1, 4, t2_W1, WT3, 512, 1024, 512 * 1024, 16);
    set(3, s2_W2, 4, t2_W2, WT4, 1024, 512, 1024 * 512, 16);
    set(4, ch_W1, 1, bt_W1, WT5, 512, 512, 512 * 512, 3);
    set(5, ch_W2, 1, bt_W2, WT6, 512, 256, 256 * 512, 3);
    set(6, bt_W3, 2, nullptr, WT7, 256, 100, 128 * 256, 2);
    transpose_all_kernel<<<(acc_wv + 3) / 4, 256, 0, stream>>>(ta);
  }
  cvt_kernel<<<2048, 256, 0, stream>>>(user_emb, Uemb, NB * 512 / 4);
  gates1_kernel<<<NB / 4, 256, 0, stream>>>(user_emb, g1_W, g1_b, g1l_W, g1l_b, G1, G1L);

  GemmArgs ga;
  const int MB = Bc / 128;  // grid.y

  for (int c = 0; c < nchunks; ++c) {
    const int b0 = c * Bc;

    // stage 1a: 16 experts (Bc,512)x(512,1024), relu, f16 tiled -> Hc
    ga.N = 1024; ga.K = 512;
    for (int g = 0; g < 16; g++) {
      ga.A[g] = Uemb + (size_t)b0 * 512;
      ga.W[g] = WT1 + (size_t)g * 512 * 1024;
      ga.bias[g] = B1 + g * 1024;
      ga.C[g] = Hc + (size_t)g * Bc * 1024;
    }
    gemm_kernel<true, 2><<<dim3(8, MB, 16), 256, 0, stream>>>(ga);

    // stage 1b: 16 experts (Bc,1024)x(1024,512), f16 tiled -> Ec
    ga.N = 512; ga.K = 1024;
    for (int g = 0; g < 16; g++) {
      ga.A[g] = Hc + (size_t)g * Bc * 1024;
      ga.W[g] = WT2 + (size_t)g * 1024 * 512;
      ga.bias[g] = B2 + g * 512;
      ga.C[g] = Ec + (size_t)g * Bc * 512;
    }
    gemm_kernel<false, 2><<<dim3(4, MB, 16), 256, 0, stream>>>(ga);

    combine1_kernel<<<Bc / 4, 256, 0, stream>>>(
        Ec, G1 + (size_t)b0 * 8, G1L + (size_t)b0 * 16, TFh, FLh, Bc);
    gates2_kernel<<<dim3(Bc / 4, 3), 256, 0, stream>>>(TFh, g2_W, g2_b, G2c, Bc);

    // stage 2a
    ga.N = 1024; ga.K = 512;
    for (int g = 0; g < 16; g++) {
      ga.A[g] = (g < 4) ? FLh : TFh + (size_t)((g - 4) >> 2) * Bc * 512;
      ga.W[g] = WT3 + (size_t)g * 512 * 1024;
      ga.bias[g] = B3 + g * 1024;
      ga.C[g] = Hc + (size_t)g * Bc * 1024;
    }
    gemm_kernel<true, 2><<<dim3(8, MB, 16), 256, 0, stream>>>(ga);

    // stage 2b
    ga.N = 512; ga.K = 1024;
    for (int g = 0; g < 16; g++) {
      ga.A[g] = Hc + (size_t)g * Bc * 1024;
      ga.W[g] = WT4 + (size_t)g * 1024 * 512;
      ga.bias[g] = B4 + g * 512;
      ga.C[g] = Ec + (size_t)g * Bc * 512;
    }
    gemm_kernel<false, 2><<<dim3(4, MB, 16), 256, 0, stream>>>(ga);

    combine2_kernel<<<dim3(Bc / 4, 3), 256, 0, stream>>>(Ec, G2c, TINc, Bc);

    // towers L1: 3 groups (Bc,512)x(512,512) relu -> TW1c tiled
    ga.N = 512; ga.K = 512;
    for (int g = 0; g < 3; g++) {
      ga.A[g] = TINc + (size_t)g * Bc * 512;
      ga.W[g] = WT5 + (size_t)g * 512 * 512;
      ga.bias[g] = BT1 + g * 512;
      ga.C[g] = TW1c + (size_t)g * Bc * 512;
    }
    for (int g = 3; g < 16; g++) { ga.A[g] = ga.A[0]; ga.W[g] = ga.W[0]; ga.bias[g] = ga.bias[0]; ga.C[g] = ga.C[0]; }
    gemm_kernel<true, 2><<<dim3(4, MB, 3), 256, 0, stream>>>(ga);

    // towers L2: 3 groups (Bc,512)x(512,256) relu -> TW2c tiled
    ga.N = 256; ga.K = 512;
    for (int g = 0; g < 3; g++) {
      ga.A[g] = TW1c + (size_t)g * Bc * 512;
      ga.W[g] = WT6 + (size_t)g * 256 * 512;
      ga.bias[g] = BT2 + g * 256;
      ga.C[g] = TW2c + (size_t)g * Bc * 256;
    }
    for (int g = 3; g < 16; g++) { ga.A[g] = ga.A[0]; ga.W[g] = ga.W[0]; ga.bias[g] = ga.bias[0]; ga.C[g] = ga.C[0]; }
    gemm_kernel<true, 2><<<dim3(2, MB, 3), 256, 0, stream>>>(ga);

    churn_l3_kernel<<<Bc / 4, 256, 0, stream>>>(TW2c, ch_W3, ch_b3,
                                                (float*)d_out + b0);

    // bt heads: 2 groups (Bc,256)x(256,100 padded 128) -> d_out f32 row-major
    ga.N = 100; ga.K = 256;
    for (int g = 0; g < 2; g++) {
      ga.A[g] = TW2c + (size_t)(1 + g) * Bc * 256;
      ga.W[g] = WT7 + (size_t)g * 128 * 256;
      ga.bias[g] = bt_b3 + g * 100;
      ga.C[g] = (float*)d_out + NB + (size_t)g * NB * 100 + (size_t)b0 * 100;
    }
    for (int g = 2; g < 16; g++) { ga.A[g] = ga.A[0]; ga.W[g] = ga.W[0]; ga.bias[g] = ga.bias[0]; ga.C[g] = ga.C[0]; }
    gemm_kernel<false, 0><<<dim3(1, MB, 2), 256, 0, stream>>>(ga);
  }
}